// Round 6
// baseline (496.523 us; speedup 1.0000x reference)
//
#include <hip/hip_runtime.h>

#define Bsz 4096
#define Tt  256
#define Ff  32
#define H1  64
#define H2  32
#define NTAPS 3
#define BT  8       // 512 blocks -> 2 blocks/CU, 4 waves/SIMD (2 indep chains/SIMD)
#define NTHR 512    // 8 waves: 0-3 L1+XG(reg-held x, reg-held xg), 4-7 L2
#define HDS 33

typedef _Float16 half8  __attribute__((ext_vector_type(8)));
typedef __fp16   fp16x2 __attribute__((ext_vector_type(2)));   // cvt_pkrtz return type
typedef float    f32x4  __attribute__((ext_vector_type(4)));

// fused LSTM unit: 5 exp + 2 rcp (f/ig reciprocals merged, algebraically exact)
__device__ __forceinline__ float lstm_unit(float pi, float pf, float pg, float po,
                                           float& c) {
    const float K1 = 1.4426950408889634f;   // log2(e)
    float ei = __builtin_amdgcn_exp2f(-K1 * pi);
    float ef = __builtin_amdgcn_exp2f(-K1 * pf);
    float eg = __builtin_amdgcn_exp2f(-2.0f * K1 * __builtin_fabsf(pg));
    float eo = __builtin_amdgcn_exp2f(-K1 * po);
    float p1 = (1.0f + ei) * (1.0f + eg);
    float pf1 = 1.0f + ef;
    float R  = __builtin_amdgcn_rcpf(p1 * pf1);          // 1/((1+ei)(1+eg)(1+ef))
    float t1 = c * p1;                                    // c*(1+ei)(1+eg)
    float t2 = __builtin_copysignf(1.0f - eg, pg) * pf1;  // tanh(g)num*sig(i)num*(1+ef)
    c = (t1 + t2) * R;                                    // f*c + i*g
    float ec = __builtin_amdgcn_exp2f(-2.0f * K1 * __builtin_fabsf(c));
    float th = (1.0f - ec) * __builtin_amdgcn_rcpf((1.0f + eo) * (1.0f + ec));
    return __builtin_copysignf(th, c);                    // o*tanh(c)
}

#define MFMA16(a, b, c) __builtin_amdgcn_mfma_f32_16x16x32_f16((a), (b), (c), 0, 0, 0)

__device__ __forceinline__ half8 cvt8(f32x4 lo, f32x4 hi) {
    union { half8 v; fp16x2 h[4]; } ax;
    ax.h[0] = __builtin_amdgcn_cvt_pkrtz(lo[0], lo[1]);
    ax.h[1] = __builtin_amdgcn_cvt_pkrtz(lo[2], lo[3]);
    ax.h[2] = __builtin_amdgcn_cvt_pkrtz(hi[0], hi[1]);
    ax.h[3] = __builtin_amdgcn_cvt_pkrtz(hi[2], hi[3]);
    return ax.v;
}

// (NTHR,2): allows up to 128 VGPR (empirically (NTHR,4) caps at 64 -> spill).
__global__ __launch_bounds__(NTHR, 2)
void lstm2_fused(const float* __restrict__ x,
                 const float* __restrict__ Wih1, const float* __restrict__ Whh1,
                 const float* __restrict__ bih1, const float* __restrict__ bhh1,
                 const float* __restrict__ Wih2, const float* __restrict__ Whh2,
                 const float* __restrict__ bih2, const float* __restrict__ bhh2,
                 const float* __restrict__ Whead, const float* __restrict__ bhead,
                 float* __restrict__ out)
{
    // Fragment-ordered h buffers: [buf][k-block][batch][8 halves].
    // a0/a1/ah read = lane(q,row8) -> 16B slot (q*8+row8): 32 distinct slots,
    // 2-way same-address broadcast (free) -> conflict-free b128 sweep.
    __shared__ __align__(16) _Float16 sH1f[2][8][BT][8];   // 2 KB
    __shared__ __align__(16) _Float16 sH2f[2][4][BT][8];   // 1 KB
    __shared__ __align__(16) float    sHead[BT][HDS];      // ~1 KB

    const int tid  = threadIdx.x;
    const int wid  = tid >> 6;        // 0..7
    const int lane = tid & 63;
    const int l15  = lane & 15;
    const int q    = lane >> 4;       // 0..3
    const int row8 = l15 & 7;         // A-frag rows duplicate with period 8 (BT=8)
    const int b0   = blockIdx.x * BT;
    const int u    = wid & 3;         // L1: h-tile; L2: sub-role index
    const bool isL1 = (wid < 4);

    // L1: wave owns h1-tile u; lane applies lstm to 2 of its 4 acc rows
    const int colL1 = u * 16 + l15;
    const int r0  = (q >> 1) * 2, r1v = r0 + 1;
    const int bLo = (q & 1) * 4 + (q >> 1) * 2;
    const int kb1 = colL1 >> 3, sb1 = colL1 & 7;     // write slot for h1
    // L2: pairs (u&1 = tile), rh = u>>1 splits the rows -> 1 lstm/lane
    const int hT = u & 1, rh = u >> 1;
    const int rL2 = (q >> 1) * 2 + rh;
    const int bL2 = (q & 1) * 4 + (q >> 1) * 2 + rh;
    const int col2 = hT * 16 + l15;
    const int kb2 = col2 >> 3, sb2 = col2 & 7;       // write slot for h2

    // per-lane x source: batch row8, features q*8..q*8+7 (8 f32 = 2 x dwordx4)
    const float* gx = x + (size_t)(b0 + row8) * Tt * Ff + q * 8;

    // ---- weight fragments (registers, one time) ----
    // L1: [G][0,1] = Whh1 h-tiles, [G][2] = Wih1 (XG); bias = bih1+bhh1 (seeds xg)
    // L2: [G][0] = Whh2, [G][1,2] = Wih2;              bias = bih2+bhh2
    half8 wH[4][3];
    float bias[4];
    if (isL1) {
        #pragma unroll
        for (int G = 0; G < 4; ++G) {
            int gr = G * 64 + colL1;               // L1 gate row
            #pragma unroll
            for (int c = 0; c < 2; ++c) {
                half8 v;
                #pragma unroll
                for (int e = 0; e < 8; ++e)
                    v[e] = (_Float16)Whh1[gr * H1 + c * 32 + q * 8 + e];
                wH[G][c] = v;
            }
            half8 vx;
            #pragma unroll
            for (int e = 0; e < 8; ++e)
                vx[e] = (_Float16)Wih1[gr * Ff + q * 8 + e];
            wH[G][2] = vx;
            bias[G] = bih1[gr] + bhh1[gr];
        }
    } else {
        #pragma unroll
        for (int G = 0; G < 4; ++G) {
            int gr2 = G * 32 + col2;               // L2 gate row
            half8 v0, v1, v2;
            #pragma unroll
            for (int e = 0; e < 8; ++e) {
                int k = q * 8 + e;
                v0[e] = (_Float16)Whh2[gr2 * H2 + k];
                v1[e] = (_Float16)Wih2[gr2 * H1 + k];
                v2[e] = (_Float16)Wih2[gr2 * H1 + 32 + k];
            }
            wH[G][0] = v0; wH[G][1] = v1; wH[G][2] = v2;
            bias[G] = bih2[gr2] + bhh2[gr2];
        }
    }

    // ---- zero h(-1) buffers (tiny now) ----
    for (int idx = tid; idx < 2 * 8 * BT * 8; idx += NTHR) ((_Float16*)sH1f)[idx] = (_Float16)0.0f;
    for (int idx = tid; idx < 2 * 4 * BT * 8; idx += NTHR) ((_Float16*)sH2f)[idx] = (_Float16)0.0f;

    // ---- XG prologue (L1): xg(0) from x(0); prefetch x(1) into buffer A ----
    f32x4 xgN[4];
    f32x4 xA_lo, xA_hi, xB_lo, xB_hi;
    if (isL1) {
        f32x4 lo = *(const f32x4*)(gx);
        f32x4 hi = *(const f32x4*)(gx + 4);
        half8 ax = cvt8(lo, hi);
        #pragma unroll
        for (int G = 0; G < 4; ++G) {
            f32x4 a = {bias[G], bias[G], bias[G], bias[G]};
            xgN[G] = MFMA16(ax, wH[G][2], a);
        }
        xA_lo = *(const f32x4*)(gx + Ff);        // x(1)
        xA_hi = *(const f32x4*)(gx + Ff + 4);
    }

    __syncthreads();   // init writes visible

    float cs0 = 0.0f, cs1 = 0.0f;

    #pragma unroll 2
    for (int i = 0; i < Tt; ++i) {
        const int cur = i & 1, nxt = cur ^ 1;

        // h1(i-1) fragments (L1 A-operand; L2 K-part operand) — conflict-free sweep
        half8 a0 = *(const half8*)&sH1f[nxt][q][row8][0];
        half8 a1 = *(const half8*)&sH1f[nxt][4 + q][row8][0];

        if (isL1) {
            // ---- prefetch x(i+2) at step TOP into the non-consume buffer:
            //      ~full step before the barrier's vmcnt drain -> latency hidden
            if (i + 2 < Tt) {
                const float* gp = gx + (size_t)(i + 2) * Ff;
                if (cur == 0) { xB_lo = *(const f32x4*)gp; xB_hi = *(const f32x4*)(gp + 4); }
                else          { xA_lo = *(const f32x4*)gp; xA_hi = *(const f32x4*)(gp + 4); }
            }

            // ---- L1 step i: acc seeded from reg-held xg, 8 MFMAs, 2 lstm ----
            f32x4 acc[4];
            #pragma unroll
            for (int G = 0; G < 4; ++G) {
                f32x4 a = xgN[G];
                a = MFMA16(a0, wH[G][0], a);
                a = MFMA16(a1, wH[G][1], a);
                acc[G] = a;
            }
            float h0  = lstm_unit(acc[0][r0],  acc[1][r0],  acc[2][r0],  acc[3][r0],  cs0);
            float h1v = lstm_unit(acc[0][r1v], acc[1][r1v], acc[2][r1v], acc[3][r1v], cs1);
            sH1f[cur][kb1][bLo][sb1]     = (_Float16)h0;
            sH1f[cur][kb1][bLo + 1][sb1] = (_Float16)h1v;

            // ---- XG: xg(i+1) from x(i+1) (prefetched last step) ----
            if (i + 1 < Tt) {
                half8 ax = (cur == 0) ? cvt8(xA_lo, xA_hi) : cvt8(xB_lo, xB_hi);
                #pragma unroll
                for (int G = 0; G < 4; ++G) {
                    f32x4 a = {bias[G], bias[G], bias[G], bias[G]};
                    xgN[G] = MFMA16(ax, wH[G][2], a);
                }
            }
        } else if (i >= 1) {   // ---- L2 step i-1 (MFMAs dup per pair; 1 lstm/lane) ----
            half8 ah = *(const half8*)&sH2f[cur][q][row8][0];
            f32x4 acc[4];
            #pragma unroll
            for (int G = 0; G < 4; ++G) {
                f32x4 a = {bias[G], bias[G], bias[G], bias[G]};
                a = MFMA16(ah, wH[G][0], a);
                a = MFMA16(a0, wH[G][1], a);
                a = MFMA16(a1, wH[G][2], a);
                acc[G] = a;
            }
            float hA = lstm_unit(acc[0][rL2], acc[1][rL2], acc[2][rL2], acc[3][rL2], cs0);
            sH2f[nxt][kb2][bL2][sb2] = (_Float16)hA;
        }

        __syncthreads();   // single barrier per step
    }

    // ---- epilogue: final L2 step (t = Tt-1) -> sHead ----
    {
        const int cur = Tt & 1;        // 0
        const int nxt = cur ^ 1;       // 1
        if (!isL1) {
            half8 a0 = *(const half8*)&sH1f[nxt][q][row8][0];
            half8 a1 = *(const half8*)&sH1f[nxt][4 + q][row8][0];
            half8 ah = *(const half8*)&sH2f[cur][q][row8][0];
            f32x4 acc[4];
            #pragma unroll
            for (int G = 0; G < 4; ++G) {
                f32x4 a = {bias[G], bias[G], bias[G], bias[G]};
                a = MFMA16(ah, wH[G][0], a);
                a = MFMA16(a0, wH[G][1], a);
                a = MFMA16(a1, wH[G][2], a);
                acc[G] = a;
            }
            float hA = lstm_unit(acc[0][rL2], acc[1][rL2], acc[2][rL2], acc[3][rL2], cs0);
            sHead[bL2][col2] = hA;
        }
        __syncthreads();
    }

    // ---- head ----
    if (tid < BT * NTAPS) {
        int b = tid / NTAPS, n = tid - b * NTAPS;
        float s = bhead[n];
        #pragma unroll
        for (int k = 0; k < H2; ++k) s = fmaf(sHead[b][k], Whead[n * H2 + k], s);
        out[(size_t)(b0 + b) * NTAPS + n] = s;
    }
}

extern "C" void kernel_launch(void* const* d_in, const int* in_sizes, int n_in,
                              void* d_out, int out_size, void* d_ws, size_t ws_size,
                              hipStream_t stream) {
    const float* xp    = (const float*)d_in[0];
    const float* Wih1  = (const float*)d_in[1];
    const float* Whh1  = (const float*)d_in[2];
    const float* bih1  = (const float*)d_in[3];
    const float* bhh1  = (const float*)d_in[4];
    const float* Wih2  = (const float*)d_in[5];
    const float* Whh2  = (const float*)d_in[6];
    const float* bih2  = (const float*)d_in[7];
    const float* bhh2  = (const float*)d_in[8];
    const float* Whead = (const float*)d_in[9];
    const float* bhead = (const float*)d_in[10];
    float* outp = (float*)d_out;

    hipLaunchKernelGGL(lstm2_fused, dim3(Bsz / BT), dim3(NTHR), 0, stream,
                       xp, Wih1, Whh1, bih1, bhh1, Wih2, Whh2, bih2, bhh2,
                       Whead, bhead, outp);
}

// Round 7
// 381.541 us; speedup vs baseline: 1.3014x; 1.3014x over previous
//
#include <hip/hip_runtime.h>

#define Bsz 4096
#define Tt  256
#define Ff  32
#define H1  64
#define H2  32
#define NTAPS 3
#define BT  8       // 512 blocks -> 2 blocks/CU, 4 waves/SIMD (2 indep chains/SIMD)
#define NTHR 512    // 8 waves: 0-3 L1+XG(reg-held xg), 4-7 L2+DMA
#define CH  16      // x-staging chunk (timesteps)
#define HDS 33

typedef _Float16 half8  __attribute__((ext_vector_type(8)));
typedef __fp16   fp16x2 __attribute__((ext_vector_type(2)));   // cvt_pkrtz return type
typedef float    f32x4  __attribute__((ext_vector_type(4)));

// fused LSTM unit: 5 exp + 2 rcp (f/ig reciprocals merged, algebraically exact)
__device__ __forceinline__ float lstm_unit(float pi, float pf, float pg, float po,
                                           float& c) {
    const float K1 = 1.4426950408889634f;   // log2(e)
    float ei = __builtin_amdgcn_exp2f(-K1 * pi);
    float ef = __builtin_amdgcn_exp2f(-K1 * pf);
    float eg = __builtin_amdgcn_exp2f(-2.0f * K1 * __builtin_fabsf(pg));
    float eo = __builtin_amdgcn_exp2f(-K1 * po);
    float p1 = (1.0f + ei) * (1.0f + eg);
    float pf1 = 1.0f + ef;
    float R  = __builtin_amdgcn_rcpf(p1 * pf1);          // 1/((1+ei)(1+eg)(1+ef))
    float t1 = c * p1;                                    // c*(1+ei)(1+eg)
    float t2 = __builtin_copysignf(1.0f - eg, pg) * pf1;  // tanh(g)num*sig(i)num*(1+ef)
    c = (t1 + t2) * R;                                    // f*c + i*g
    float ec = __builtin_amdgcn_exp2f(-2.0f * K1 * __builtin_fabsf(c));
    float th = (1.0f - ec) * __builtin_amdgcn_rcpf((1.0f + eo) * (1.0f + ec));
    return __builtin_copysignf(th, c);                    // o*tanh(c)
}

#define MFMA16(a, b, c) __builtin_amdgcn_mfma_f32_16x16x32_f16((a), (b), (c), 0, 0, 0)

// async global->LDS DMA, 16B per lane; LDS dst = uniform base + lane*16
__device__ __forceinline__ void dma16(const float* gp, const float* lp) {
    __builtin_amdgcn_global_load_lds(
        (const __attribute__((address_space(1))) void*)gp,
        (__attribute__((address_space(3))) void*)lp, 16, 0, 0);
}

__device__ __forceinline__ half8 cvt8(f32x4 lo, f32x4 hi) {
    union { half8 v; fp16x2 h[4]; } ax;
    ax.h[0] = __builtin_amdgcn_cvt_pkrtz(lo[0], lo[1]);
    ax.h[1] = __builtin_amdgcn_cvt_pkrtz(lo[2], lo[3]);
    ax.h[2] = __builtin_amdgcn_cvt_pkrtz(hi[0], hi[1]);
    ax.h[3] = __builtin_amdgcn_cvt_pkrtz(hi[2], hi[3]);
    return ax.v;
}

// (NTHR,2): allows up to 128 VGPR (empirically (NTHR,4) caps at 64 -> spill).
__global__ __launch_bounds__(NTHR, 2)
void lstm2_fused(const float* __restrict__ x,
                 const float* __restrict__ Wih1, const float* __restrict__ Whh1,
                 const float* __restrict__ bih1, const float* __restrict__ bhh1,
                 const float* __restrict__ Wih2, const float* __restrict__ Whh2,
                 const float* __restrict__ bih2, const float* __restrict__ bhh2,
                 const float* __restrict__ Whead, const float* __restrict__ bhead,
                 float* __restrict__ out)
{
    // Fragment-ordered h buffers: [buf][k-block][batch][8 halves].
    // a0/a1/ah read = lane(q,row8) -> 16B slot (q*8+row8): 32 distinct slots,
    // 2-way same-address broadcast (free) -> conflict-free b128 sweep.
    __shared__ __align__(16) _Float16 sH1f[2][8][BT][8];   // 2 KB
    __shared__ __align__(16) _Float16 sH2f[2][4][BT][8];   // 1 KB
    // x chunk: [buf][t][f4][b][4] f32 — (f4-major, b-minor), DMA lane*16B contiguous
    __shared__ __align__(16) float    sXC[2][CH][8][BT][4]; // 32 KB
    __shared__ __align__(16) float    sHead[BT][HDS];       // ~1 KB

    const int tid  = threadIdx.x;
    const int wid  = tid >> 6;        // 0..7
    const int lane = tid & 63;
    const int l15  = lane & 15;
    const int q    = lane >> 4;       // 0..3
    const int row8 = l15 & 7;         // A-frag rows duplicate with period 8 (BT=8)
    const int b0   = blockIdx.x * BT;
    const int u    = wid & 3;         // L1: h-tile; L2: sub-role index
    const bool isL1 = (wid < 4);

    // L1: wave owns h1-tile u; lane applies lstm to 2 of its 4 acc rows
    const int colL1 = u * 16 + l15;
    const int r0  = (q >> 1) * 2, r1v = r0 + 1;
    const int bLo = (q & 1) * 4 + (q >> 1) * 2;
    const int kb1 = colL1 >> 3, sb1 = colL1 & 7;     // write slot for h1
    // L2: pairs (u&1 = tile), rh = u>>1 splits the rows -> 1 lstm/lane
    const int hT = u & 1, rh = u >> 1;
    const int rL2 = (q >> 1) * 2 + rh;
    const int bL2 = (q & 1) * 4 + (q >> 1) * 2 + rh;
    const int col2 = hT * 16 + l15;
    const int kb2 = col2 >> 3, sb2 = col2 & 7;       // write slot for h2

    // per-lane DMA source base: batch bL, float-quad f4L
    const int bL  = lane & 7;
    const int f4L = lane >> 3;
    const float* gbase = x + (size_t)(b0 + bL) * Tt * Ff + f4L * 4;

    // ---- prologue: waves 4-7 kick chunk 0 DMA immediately ----
    if (!isL1) {
        #pragma unroll
        for (int j = 0; j < 4; ++j) {
            int tl = u * 4 + j;
            dma16(gbase + (size_t)tl * Ff, &sXC[0][tl][0][0][0]);
        }
    }

    // ---- weight fragments (registers, one time) ----
    // L1: [G][0,1] = Whh1 h-tiles, [G][2] = Wih1 (XG); bias = bih1+bhh1 (seeds xg)
    // L2: [G][0] = Whh2, [G][1,2] = Wih2;              bias = bih2+bhh2
    half8 wH[4][3];
    float bias[4];
    if (isL1) {
        #pragma unroll
        for (int G = 0; G < 4; ++G) {
            int gr = G * 64 + colL1;               // L1 gate row
            #pragma unroll
            for (int c = 0; c < 2; ++c) {
                half8 v;
                #pragma unroll
                for (int e = 0; e < 8; ++e)
                    v[e] = (_Float16)Whh1[gr * H1 + c * 32 + q * 8 + e];
                wH[G][c] = v;
            }
            half8 vx;
            #pragma unroll
            for (int e = 0; e < 8; ++e)
                vx[e] = (_Float16)Wih1[gr * Ff + q * 8 + e];
            wH[G][2] = vx;
            bias[G] = bih1[gr] + bhh1[gr];
        }
    } else {
        #pragma unroll
        for (int G = 0; G < 4; ++G) {
            int gr2 = G * 32 + col2;               // L2 gate row
            half8 v0, v1, v2;
            #pragma unroll
            for (int e = 0; e < 8; ++e) {
                int k = q * 8 + e;
                v0[e] = (_Float16)Whh2[gr2 * H2 + k];
                v1[e] = (_Float16)Wih2[gr2 * H1 + k];
                v2[e] = (_Float16)Wih2[gr2 * H1 + 32 + k];
            }
            wH[G][0] = v0; wH[G][1] = v1; wH[G][2] = v2;
            bias[G] = bih2[gr2] + bhh2[gr2];
        }
    }

    // ---- zero h(-1) buffers (tiny) ----
    for (int idx = tid; idx < 2 * 8 * BT * 8; idx += NTHR) ((_Float16*)sH1f)[idx] = (_Float16)0.0f;
    for (int idx = tid; idx < 2 * 4 * BT * 8; idx += NTHR) ((_Float16*)sH2f)[idx] = (_Float16)0.0f;

    __syncthreads();   // drains chunk-0 DMA + init writes

    // ---- XG prologue (L1): xg(0) from staged x(0) ----
    f32x4 xgN[4];
    if (isL1) {
        f32x4 lo = *(const f32x4*)&sXC[0][0][2 * q][row8][0];
        f32x4 hi = *(const f32x4*)&sXC[0][0][2 * q + 1][row8][0];
        half8 ax = cvt8(lo, hi);
        #pragma unroll
        for (int G = 0; G < 4; ++G) {
            f32x4 a = {bias[G], bias[G], bias[G], bias[G]};
            xgN[G] = MFMA16(ax, wH[G][2], a);
        }
    }

    float cs0 = 0.0f, cs1 = 0.0f;

    #pragma unroll 2
    for (int i = 0; i < Tt; ++i) {
        const int cur = i & 1, nxt = cur ^ 1;
        const int cbuf = (i >> 4) & 1;

        // ---- chunk-boundary DMA at TOP of step (latency hides under compute) ----
        if (!isL1 && (i & (CH - 1)) == 0 && i + CH < Tt) {
            const float* gb = gbase + (size_t)(i + CH) * Ff;
            #pragma unroll
            for (int j = 0; j < 4; ++j) {
                int tl = u * 4 + j;
                dma16(gb + (size_t)tl * Ff, &sXC[cbuf ^ 1][tl][0][0][0]);
            }
        }

        // h1(i-1) fragments (L1 A-operand; L2 K-part operand) — conflict-free sweep
        half8 a0 = *(const half8*)&sH1f[nxt][q][row8][0];
        half8 a1 = *(const half8*)&sH1f[nxt][4 + q][row8][0];

        if (isL1) {   // ---- L1 step i: acc seeded from reg-held xg, 8 MFMAs, 2 lstm ----
            f32x4 acc[4];
            #pragma unroll
            for (int G = 0; G < 4; ++G) {
                f32x4 a = xgN[G];
                a = MFMA16(a0, wH[G][0], a);
                a = MFMA16(a1, wH[G][1], a);
                acc[G] = a;
            }
            float h0  = lstm_unit(acc[0][r0],  acc[1][r0],  acc[2][r0],  acc[3][r0],  cs0);
            float h1v = lstm_unit(acc[0][r1v], acc[1][r1v], acc[2][r1v], acc[3][r1v], cs1);
            sH1f[cur][kb1][bLo][sb1]     = (_Float16)h0;
            sH1f[cur][kb1][bLo + 1][sb1] = (_Float16)h1v;

            if (i + 1 < Tt) {   // ---- XG: xg(i+1) from staged x(i+1) ----
                const int t = i + 1, cb = (t >> 4) & 1, t16 = t & (CH - 1);
                f32x4 lo = *(const f32x4*)&sXC[cb][t16][2 * q][row8][0];
                f32x4 hi = *(const f32x4*)&sXC[cb][t16][2 * q + 1][row8][0];
                half8 ax = cvt8(lo, hi);
                #pragma unroll
                for (int G = 0; G < 4; ++G) {
                    f32x4 a = {bias[G], bias[G], bias[G], bias[G]};
                    xgN[G] = MFMA16(ax, wH[G][2], a);
                }
            }
        } else if (i >= 1) {   // ---- L2 step i-1 (MFMAs dup per pair; 1 lstm/lane) ----
            half8 ah = *(const half8*)&sH2f[cur][q][row8][0];
            f32x4 acc[4];
            #pragma unroll
            for (int G = 0; G < 4; ++G) {
                f32x4 a = {bias[G], bias[G], bias[G], bias[G]};
                a = MFMA16(ah, wH[G][0], a);
                a = MFMA16(a0, wH[G][1], a);
                a = MFMA16(a1, wH[G][2], a);
                acc[G] = a;
            }
            float hA = lstm_unit(acc[0][rL2], acc[1][rL2], acc[2][rL2], acc[3][rL2], cs0);
            sH2f[nxt][kb2][bL2][sb2] = (_Float16)hA;
        }

        __syncthreads();   // single barrier per step
    }

    // ---- epilogue: final L2 step (t = Tt-1) -> sHead ----
    {
        const int cur = Tt & 1;        // 0
        const int nxt = cur ^ 1;       // 1
        if (!isL1) {
            half8 a0 = *(const half8*)&sH1f[nxt][q][row8][0];
            half8 a1 = *(const half8*)&sH1f[nxt][4 + q][row8][0];
            half8 ah = *(const half8*)&sH2f[cur][q][row8][0];
            f32x4 acc[4];
            #pragma unroll
            for (int G = 0; G < 4; ++G) {
                f32x4 a = {bias[G], bias[G], bias[G], bias[G]};
                a = MFMA16(ah, wH[G][0], a);
                a = MFMA16(a0, wH[G][1], a);
                a = MFMA16(a1, wH[G][2], a);
                acc[G] = a;
            }
            float hA = lstm_unit(acc[0][rL2], acc[1][rL2], acc[2][rL2], acc[3][rL2], cs0);
            sHead[bL2][col2] = hA;
        }
        __syncthreads();
    }

    // ---- head ----
    if (tid < BT * NTAPS) {
        int b = tid / NTAPS, n = tid - b * NTAPS;
        float s = bhead[n];
        #pragma unroll
        for (int k = 0; k < H2; ++k) s = fmaf(sHead[b][k], Whead[n * H2 + k], s);
        out[(size_t)(b0 + b) * NTAPS + n] = s;
    }
}

extern "C" void kernel_launch(void* const* d_in, const int* in_sizes, int n_in,
                              void* d_out, int out_size, void* d_ws, size_t ws_size,
                              hipStream_t stream) {
    const float* xp    = (const float*)d_in[0];
    const float* Wih1  = (const float*)d_in[1];
    const float* Whh1  = (const float*)d_in[2];
    const float* bih1  = (const float*)d_in[3];
    const float* bhh1  = (const float*)d_in[4];
    const float* Wih2  = (const float*)d_in[5];
    const float* Whh2  = (const float*)d_in[6];
    const float* bih2  = (const float*)d_in[7];
    const float* bhh2  = (const float*)d_in[8];
    const float* Whead = (const float*)d_in[9];
    const float* bhead = (const float*)d_in[10];
    float* outp = (float*)d_out;

    hipLaunchKernelGGL(lstm2_fused, dim3(Bsz / BT), dim3(NTHR), 0, stream,
                       xp, Wih1, Whh1, bih1, bhh1, Wih2, Whh2, bih2, bhh2,
                       Whead, bhead, outp);
}